// Round 16
// baseline (444.922 us; speedup 1.0000x reference)
//
#include <hip/hip_runtime.h>
#include <math.h>

typedef short short8 __attribute__((ext_vector_type(8)));
typedef float f32x4 __attribute__((ext_vector_type(4)));

__device__ __forceinline__ unsigned short f2bf(float f){   // RTN bf16
    unsigned u = __float_as_uint(f);
    unsigned r = u + 0x7fffu + ((u >> 16) & 1u);
    return (unsigned short)(r >> 16);
}

// ---------------- CSR build ----------------
__global__ void k_count(const int* __restrict__ ef, const int* __restrict__ er,
                        int* __restrict__ deg, int Ef, int Er)
{
    int Etot = Ef + Er;
    for (int e = blockIdx.x*blockDim.x + threadIdx.x; e < Etot; e += gridDim.x*blockDim.x) {
        int dst = (e < Ef) ? ef[Ef + e] : er[Er + (e - Ef)];
        atomicAdd(&deg[dst], 1);
    }
}

__global__ void k_chunk_sums(const int* __restrict__ deg, int* __restrict__ csum, int n)
{
    __shared__ int s[256];
    int t = threadIdx.x, i = blockIdx.x*256 + t;
    s[t] = (i < n) ? deg[i] : 0;
    __syncthreads();
    for (int off = 128; off > 0; off >>= 1) {
        if (t < off) s[t] += s[t + off];
        __syncthreads();
    }
    if (t == 0) csum[blockIdx.x] = s[0];
}

__global__ void k_scan_chunks(int* __restrict__ csum, int nch)
{
    __shared__ int s[1024];
    int t = threadIdx.x;
    int v = (t < nch) ? csum[t] : 0;
    s[t] = v; __syncthreads();
    for (int off = 1; off < 1024; off <<= 1) {
        int u = (t >= off) ? s[t - off] : 0;
        __syncthreads();
        s[t] += u;
        __syncthreads();
    }
    if (t < nch) csum[t] = s[t] - v;
}

__global__ void k_rowstart(const int* __restrict__ deg, const int* __restrict__ csum,
                           int* __restrict__ row_start, int* __restrict__ cursor, int n)
{
    __shared__ int s[256];
    int t = threadIdx.x, i = blockIdx.x*256 + t;
    int d = (i < n) ? deg[i] : 0;
    s[t] = d; __syncthreads();
    for (int off = 1; off < 256; off <<= 1) {
        int u = (t >= off) ? s[t - off] : 0;
        __syncthreads();
        s[t] += u;
        __syncthreads();
    }
    if (i <= n) {
        int rs = csum[blockIdx.x] + s[t] - d;
        row_start[i] = rs;
        cursor[i] = rs;
    }
}

__global__ void k_fill(const int* __restrict__ ef, const int* __restrict__ er,
                       int* __restrict__ cursor, unsigned* __restrict__ srcs,
                       int Ef, int Er, int n_nodes)
{
    int Etot = Ef + Er;
    if (blockIdx.x == 0 && threadIdx.x == 0) { srcs[Etot] = 0; srcs[Etot + 1] = 0; }
    for (int e = blockIdx.x*blockDim.x + threadIdx.x; e < Etot; e += gridDim.x*blockDim.x) {
        int src, dst, tt;
        if (e < Ef) { src = ef[e]; dst = ef[Ef + e]; tt = 0; }
        else { int e2 = e - Ef; src = er[e2]; dst = er[Er + e2]; tt = 1; }
        int pos = atomicAdd(&cursor[dst], 1);
        srcs[pos] = (unsigned)(tt*n_nodes + src)*32u;
    }
}

// ---------------- mega setup: compose kqv + compose out + in_w^T + x cast
//                  + deg zero + logits init (head bias) ----------------
__global__ void k_setup(const float* __restrict__ kqv_w, const float* __restrict__ kqv_b,
                        const float* __restrict__ krel_w, const float* __restrict__ vrel_w,
                        const float* __restrict__ p_rel, const float* __restrict__ out_w,
                        const float* __restrict__ out_b, const float* __restrict__ in_w,
                        const float* __restrict__ x, const float* __restrict__ head_b,
                        unsigned short* __restrict__ WcT, float* __restrict__ biasc,
                        unsigned short* __restrict__ WoT, float* __restrict__ biaso,
                        unsigned short* __restrict__ WiT, unsigned short* __restrict__ x16,
                        int* __restrict__ deg, float* __restrict__ logits, int n_nodes)
{
    const int N0 = 2*129*640;            // compose kqv
    const int N1 = N0 + 2*129*128;       // compose out
    const int N2 = N1 + 128*128;         // in_w transpose
    const long long N3 = (long long)N2 + (long long)n_nodes*32;  // x cast (4 elems/thread)
    const long long N4 = N3 + n_nodes;   // deg zero
    const long long N5 = N4 + 2*n_nodes; // logits init

    for (long long idx = (long long)blockIdx.x*blockDim.x + threadIdx.x; idx < N5;
         idx += (long long)gridDim.x*blockDim.x) {
        if (idx < N0) {
            int i = (int)idx;
            int l = i / (129*640);
            int rem = i % (129*640);
            int r = rem / 640, c = rem % 640;
            float val;
            if (c < 128) {
                val = (r < 128) ? kqv_w[((size_t)l*128 + r)*384 + 128 + c]
                                : kqv_b[l*384 + 128 + c];
            } else {
                int c2 = c - 128;
                int tt = c2 >> 8;
                int cc = c2 & 255;
                int f = cc >> 1;
                int part = cc & 1;
                int hh = f >> 4, fd = f & 15;
                const float* rw = (part == 0 ? krel_w : vrel_w)
                                  + (((size_t)(l*2 + tt)*8 + hh)*16)*16 + fd;
                int base_col = (part == 0 ? 0 : 256) + hh*16;
                float s = 0.f;
                #pragma unroll
                for (int d = 0; d < 16; ++d) {
                    float a = (r < 128) ? kqv_w[((size_t)l*128 + r)*384 + base_col + d]
                                        : kqv_b[l*384 + base_col + d];
                    s += a * rw[d*16];
                }
                if (part == 0) s *= p_rel[(l*2 + tt)*8 + hh] * 0.25f * 1.4426950408889634f;
                val = s;
            }
            if (r < 128) WcT[((size_t)l*640 + c)*128 + r] = f2bf(val);
            else         biasc[l*640 + c] = val;
        } else if (idx < N1) {
            int i = (int)(idx - N0);
            int l = i / (129*128);
            int rem = i % (129*128);
            int r = rem / 128, c = rem % 128;
            if (r < 128) WoT[((size_t)l*128 + c)*128 + r] = f2bf(out_w[((size_t)l*128 + r)*128 + c]);
            else         biaso[l*128 + c] = out_b[l*128 + c];
        } else if (idx < N2) {
            int i = (int)(idx - N1);
            int r = i >> 7, c = i & 127;
            WiT[(size_t)c*128 + r] = f2bf(in_w[(size_t)r*128 + c]);
        } else if (idx < N3) {
            long long i = idx - N2;          // 4 elems each
            float4 v = *(const float4*)&x[i*4];
            uint2 w;
            w.x = (unsigned)f2bf(v.x) | ((unsigned)f2bf(v.y) << 16);
            w.y = (unsigned)f2bf(v.z) | ((unsigned)f2bf(v.w) << 16);
            *(uint2*)&x16[i*4] = w;
        } else if (idx < N4) {
            deg[idx - N3] = 0;
        } else {
            long long i = idx - N4;
            logits[i] = head_b[i & 1];
        }
    }
}

// ---------------- LDS-staged MFMA GEMM (bf16 twins as source) ----------------
// mode 0 (in_proj): out_f = C+b; out_b16 = bf16(C+b)
// mode 1 (kqv):     cols<128 -> out_f (q f32); cols>=128 -> packed bf16 kv
// mode 2 (out_proj): out_f = relu(g*(C+b) + (1-g)*out_f); out_b16 = bf16(result)
// mode 3 (out_proj+head): nv = relu(...); logits[m] += nv . head_w  (no h store)
__global__ __launch_bounds__(256) void k_mfma(
    const unsigned short* __restrict__ A16, const unsigned short* __restrict__ WT,
    const float* __restrict__ biasc, float* __restrict__ out_f,
    unsigned short* __restrict__ out_b16, unsigned* __restrict__ kv,
    const float* __restrict__ skip, const float* __restrict__ hw,
    float* __restrict__ logits, int l,
    int n_nodes, int R, int C, int mode)
{
    __shared__ uint4 As[64*16];
    __shared__ uint4 Ws[64*16];
    int b = blockIdx.x;
    int xcd = b & 7, jj = b >> 3;
    int r_t = (jj / C)*8 + xcd;
    int c_t = jj % C;
    if (r_t >= R) return;
    int n0 = r_t*64, c0 = c_t*64;
    int t = threadIdx.x;

    #pragma unroll
    for (int it = 0; it < 4; ++it) {
        int gi = t + it*256;
        int m = gi >> 4, g = gi & 15;
        uint4 a = *(const uint4*)&A16[((size_t)(n0 + m)*16 + g)*8];
        As[m*16 + (g ^ (m & 15))] = a;
    }
    #pragma unroll
    for (int it = 0; it < 4; ++it) {
        int gi = t + it*256;
        int cw = gi >> 4, g = gi & 15;
        uint4 wv = *(const uint4*)&WT[((size_t)(c0 + cw)*16 + g)*8];
        Ws[cw*16 + (g ^ (cw & 15))] = wv;
    }
    __syncthreads();

    int lane = t & 63, w = t >> 6;
    int lm = lane & 15, quad = lane >> 4;
    f32x4 acc[4];
    #pragma unroll
    for (int i = 0; i < 4; ++i) { acc[i][0]=0.f; acc[i][1]=0.f; acc[i][2]=0.f; acc[i][3]=0.f; }

    #pragma unroll
    for (int chunk = 0; chunk < 4; ++chunk) {
        int gq = chunk*4 + quad;
        short8 bfrag = *(const short8*)&Ws[(w*16 + lm)*16 + (gq ^ lm)];
        #pragma unroll
        for (int i = 0; i < 4; ++i) {
            short8 afrag = *(const short8*)&As[(i*16 + lm)*16 + (gq ^ lm)];
            acc[i] = __builtin_amdgcn_mfma_f32_16x16x32_bf16(afrag, bfrag, acc[i], 0, 0, 0);
        }
    }

    int c = c0 + w*16 + lm;
    float bc = biasc[c];
    if (mode == 3) {
        float g = 1.f/(1.f + expf(-skip[l]));
        float hw0 = hw[c*2], hw1 = hw[c*2 + 1];
        #pragma unroll
        for (int i = 0; i < 4; ++i) {
            #pragma unroll
            for (int rr = 0; rr < 4; ++rr) {
                int m = n0 + i*16 + quad*4 + rr;
                float nv = 0.f;
                if (m < n_nodes) {
                    float hv = out_f[(size_t)m*128 + c];
                    nv = fmaxf(g*(acc[i][rr] + bc) + (1.f - g)*hv, 0.f);
                }
                float p0 = nv*hw0, p1 = nv*hw1;
                p0 += __shfl_xor(p0, 1); p1 += __shfl_xor(p1, 1);
                p0 += __shfl_xor(p0, 2); p1 += __shfl_xor(p1, 2);
                p0 += __shfl_xor(p0, 4); p1 += __shfl_xor(p1, 4);
                p0 += __shfl_xor(p0, 8); p1 += __shfl_xor(p1, 8);
                if (lm == 0 && m < n_nodes) {
                    atomicAdd(&logits[m*2],     p0);
                    atomicAdd(&logits[m*2 + 1], p1);
                }
            }
        }
    } else if (mode == 2) {
        float g = 1.f/(1.f + expf(-skip[l]));
        #pragma unroll
        for (int i = 0; i < 4; ++i) {
            #pragma unroll
            for (int rr = 0; rr < 4; ++rr) {
                int m = n0 + i*16 + quad*4 + rr;
                if (m < n_nodes) {
                    size_t o = (size_t)m*128 + c;
                    float hv = out_f[o];
                    float nv = fmaxf(g*(acc[i][rr] + bc) + (1.f - g)*hv, 0.f);
                    out_f[o] = nv;
                    out_b16[o] = f2bf(nv);
                }
            }
        }
    } else if (mode == 0) {
        #pragma unroll
        for (int i = 0; i < 4; ++i) {
            #pragma unroll
            for (int rr = 0; rr < 4; ++rr) {
                int m = n0 + i*16 + quad*4 + rr;
                if (m < n_nodes) {
                    size_t o = (size_t)m*128 + c;
                    float nv = acc[i][rr] + bc;
                    out_f[o] = nv;
                    out_b16[o] = f2bf(nv);
                }
            }
        }
    } else if (c0 < 128) {                 // kqv: q columns f32
        #pragma unroll
        for (int i = 0; i < 4; ++i) {
            #pragma unroll
            for (int rr = 0; rr < 4; ++rr) {
                int m = n0 + i*16 + quad*4 + rr;
                if (m < n_nodes) out_f[(size_t)m*128 + c] = acc[i][rr] + bc;
            }
        }
    } else {                               // kqv: packed bf16 kv via shfl pair
        int c2 = c - 128;
        int tt = c2 >> 8;
        int f = (c2 & 255) >> 1;
        unsigned* dst = kv + (size_t)tt*n_nodes*128;
        bool isk = (lane & 1) == 0;
        #pragma unroll
        for (int i = 0; i < 4; ++i) {
            #pragma unroll
            for (int rr = 0; rr < 4; ++rr) {
                float val = acc[i][rr] + bc;
                float other = __shfl_xor(val, 1);
                int m = n0 + i*16 + quad*4 + rr;
                if (isk && m < n_nodes) {
                    unsigned wd = ((unsigned)f2bf(val) << 16) | (unsigned)f2bf(other);
                    dst[(size_t)m*128 + f] = wd;
                }
            }
        }
    }
}

// ---------------- fused gather attention (exp2 domain; gelu -> bf16 qa16) ----------------
__global__ __launch_bounds__(256) void k_attn(
    const unsigned* __restrict__ srcs, const int* __restrict__ row_start,
    const uint4* __restrict__ kv, const float* __restrict__ qa,
    unsigned short* __restrict__ qa16, int n_nodes)
{
    int lane = threadIdx.x & 31;
    int n = blockIdx.x*8 + (threadIdx.x >> 5);
    if (n >= n_nodes) return;
    float4 q4 = *(const float4*)&qa[(size_t)n*128 + lane*4];
    int s = row_start[n], e = row_start[n + 1];

    float m0 = -INFINITY, l0 = 0.f; float4 a0 = make_float4(0.f,0.f,0.f,0.f);
    float m1 = -INFINITY, l1 = 0.f; float4 a1 = make_float4(0.f,0.f,0.f,0.f);

    uint4 w0n = kv[srcs[s] + lane];
    uint4 w1n = kv[srcs[s + 1] + lane];
    int pos = s;
    for (; pos + 1 < e; pos += 2) {
        uint4 w0 = w0n, w1 = w1n;
        unsigned sv0 = srcs[pos + 2], sv1 = srcs[pos + 3];
        w0n = kv[sv0 + lane];
        w1n = kv[sv1 + lane];
        float d0 = __uint_as_float(w0.x & 0xffff0000u)*q4.x
                 + __uint_as_float(w0.y & 0xffff0000u)*q4.y
                 + __uint_as_float(w0.z & 0xffff0000u)*q4.z
                 + __uint_as_float(w0.w & 0xffff0000u)*q4.w;
        float d1 = __uint_as_float(w1.x & 0xffff0000u)*q4.x
                 + __uint_as_float(w1.y & 0xffff0000u)*q4.y
                 + __uint_as_float(w1.z & 0xffff0000u)*q4.z
                 + __uint_as_float(w1.w & 0xffff0000u)*q4.w;
        d0 += __shfl_xor(d0, 1); d1 += __shfl_xor(d1, 1);
        d0 += __shfl_xor(d0, 2); d1 += __shfl_xor(d1, 2);
        float mn0 = fmaxf(m0, d0), mn1 = fmaxf(m1, d1);
        float sc0 = exp2f(m0 - mn0), sc1 = exp2f(m1 - mn1);
        float wt0 = exp2f(d0 - mn0), wt1 = exp2f(d1 - mn1);
        l0 = l0*sc0 + wt0;               l1 = l1*sc1 + wt1;
        a0.x = a0.x*sc0 + wt0*__uint_as_float(w0.x << 16);
        a1.x = a1.x*sc1 + wt1*__uint_as_float(w1.x << 16);
        a0.y = a0.y*sc0 + wt0*__uint_as_float(w0.y << 16);
        a1.y = a1.y*sc1 + wt1*__uint_as_float(w1.y << 16);
        a0.z = a0.z*sc0 + wt0*__uint_as_float(w0.z << 16);
        a1.z = a1.z*sc1 + wt1*__uint_as_float(w1.z << 16);
        a0.w = a0.w*sc0 + wt0*__uint_as_float(w0.w << 16);
        a1.w = a1.w*sc1 + wt1*__uint_as_float(w1.w << 16);
        m0 = mn0; m1 = mn1;
    }
    if (pos < e) {
        uint4 w0 = w0n;
        float d = __uint_as_float(w0.x & 0xffff0000u)*q4.x
                + __uint_as_float(w0.y & 0xffff0000u)*q4.y
                + __uint_as_float(w0.z & 0xffff0000u)*q4.z
                + __uint_as_float(w0.w & 0xffff0000u)*q4.w;
        d += __shfl_xor(d, 1);
        d += __shfl_xor(d, 2);
        float mn = fmaxf(m0, d);
        float sc = exp2f(m0 - mn);
        float wt = exp2f(d - mn);
        l0 = l0*sc + wt;
        a0.x = a0.x*sc + wt*__uint_as_float(w0.x << 16);
        a0.y = a0.y*sc + wt*__uint_as_float(w0.y << 16);
        a0.z = a0.z*sc + wt*__uint_as_float(w0.z << 16);
        a0.w = a0.w*sc + wt*__uint_as_float(w0.w << 16);
        m0 = mn;
    }
    float mn = fmaxf(m0, m1);
    float sc0 = (m0 == -INFINITY) ? 0.f : exp2f(m0 - mn);
    float sc1 = (m1 == -INFINITY) ? 0.f : exp2f(m1 - mn);
    float lsum = l0*sc0 + l1*sc1;
    float4 acc;
    acc.x = a0.x*sc0 + a1.x*sc1;
    acc.y = a0.y*sc0 + a1.y*sc1;
    acc.z = a0.z*sc0 + a1.z*sc1;
    acc.w = a0.w*sc0 + a1.w*sc1;

    float inv = 1.f/(lsum + 1e-16f);
    float x0 = acc.x*inv, x1 = acc.y*inv, x2 = acc.z*inv, x3 = acc.w*inv;
    float g0 = 0.5f*x0*(1.f + erff(x0*0.70710678118654752f));
    float g1 = 0.5f*x1*(1.f + erff(x1*0.70710678118654752f));
    float g2 = 0.5f*x2*(1.f + erff(x2*0.70710678118654752f));
    float g3 = 0.5f*x3*(1.f + erff(x3*0.70710678118654752f));
    uint2 pk;
    pk.x = (unsigned)f2bf(g0) | ((unsigned)f2bf(g1) << 16);
    pk.y = (unsigned)f2bf(g2) | ((unsigned)f2bf(g3) << 16);
    *(uint2*)&qa16[(size_t)n*128 + lane*4] = pk;
}

extern "C" void kernel_launch(void* const* d_in, const int* in_sizes, int n_in,
                              void* d_out, int out_size, void* d_ws, size_t ws_size,
                              hipStream_t stream)
{
    const float* x      = (const float*)d_in[0];
    const int*   ef     = (const int*)d_in[1];
    const int*   er     = (const int*)d_in[2];
    const float* in_w   = (const float*)d_in[3];
    const float* in_b   = (const float*)d_in[4];
    const float* kqv_w  = (const float*)d_in[5];
    const float* kqv_b  = (const float*)d_in[6];
    const float* krel_w = (const float*)d_in[7];
    const float* vrel_w = (const float*)d_in[8];
    const float* p_rel  = (const float*)d_in[9];
    const float* out_w  = (const float*)d_in[10];
    const float* out_b  = (const float*)d_in[11];
    const float* skip   = (const float*)d_in[12];
    const float* head_w = (const float*)d_in[13];
    const float* head_b = (const float*)d_in[14];
    float* out = (float*)d_out;

    int n_nodes = in_sizes[0] / 128;
    int Ef = in_sizes[1] / 2, Er = in_sizes[2] / 2;
    int Etot = Ef + Er;
    int nch = (n_nodes + 255)/256;
    int ntile = (n_nodes + 63)/64;
    int npad = ntile*64;

    // workspace
    float* p = (float*)d_ws;
    float* h    = p; p += (size_t)npad*128;
    float* qa   = p; p += (size_t)npad*128;
    unsigned* kv = (unsigned*)p; p += (size_t)2*n_nodes*128;
    unsigned short* h16  = (unsigned short*)p; p += (size_t)npad*128/2;
    unsigned short* qa16 = (unsigned short*)p; p += (size_t)npad*128/2;
    unsigned short* x16  = (unsigned short*)p; p += (size_t)npad*128/2;
    unsigned short* WiT = (unsigned short*)p; p += (size_t)(128*128)/2;
    unsigned short* WcT = (unsigned short*)p; p += (size_t)(2*640*128)/2;
    float* biasc = p; p += 2*640;
    unsigned short* WoT = (unsigned short*)p; p += (size_t)(2*128*128)/2;
    float* biaso = p; p += 2*128;
    int* deg       = (int*)p;      p += n_nodes;
    int* csum      = (int*)p;      p += 1024;
    int* row_start = (int*)p;      p += n_nodes + 1;
    int* cursor    = (int*)p;      p += n_nodes + 1;
    unsigned* srcs = (unsigned*)p; p += Etot + 2;

    int Rg = (ntile + 7)/8;

    // ---- setup (fused) + CSR build ----
    k_setup<<<7500, 256, 0, stream>>>(kqv_w, kqv_b, krel_w, vrel_w, p_rel, out_w, out_b,
                                      in_w, x, head_b, WcT, biasc, WoT, biaso, WiT, x16,
                                      deg, out, n_nodes);
    k_count<<<1024, 256, 0, stream>>>(ef, er, deg, Ef, Er);
    k_chunk_sums<<<nch, 256, 0, stream>>>(deg, csum, n_nodes);
    k_scan_chunks<<<1, 1024, 0, stream>>>(csum, nch);
    k_rowstart<<<(n_nodes + 256)/256, 256, 0, stream>>>(deg, csum, row_start, cursor, n_nodes);
    k_fill<<<1024, 256, 0, stream>>>(ef, er, cursor, srcs, Ef, Er, n_nodes);

    // ---- network ----
    k_mfma<<<Rg*8*2, 256, 0, stream>>>(x16, WiT, in_b, h, h16, kv, skip, head_w, out, 0,
                                       n_nodes, ntile, 2, 0);
    for (int l = 0; l < 2; ++l) {
        k_mfma<<<Rg*8*10, 256, 0, stream>>>(h16, WcT + (size_t)l*640*128,
                                            biasc + l*640, qa, nullptr, kv, skip,
                                            head_w, out, l, n_nodes, ntile, 10, 1);
        k_attn<<<(n_nodes + 7)/8, 256, 0, stream>>>(srcs, row_start,
                                                    (const uint4*)kv, qa, qa16, n_nodes);
        int omode = (l == 1) ? 3 : 2;
        k_mfma<<<Rg*8*2, 256, 0, stream>>>(qa16, WoT + (size_t)l*128*128,
                                           biaso + l*128, h, h16, kv, skip,
                                           head_w, out, l, n_nodes, ntile, 2, omode);
    }
}

// Round 17
// 441.914 us; speedup vs baseline: 1.0068x; 1.0068x over previous
//
#include <hip/hip_runtime.h>
#include <math.h>

typedef short short8 __attribute__((ext_vector_type(8)));
typedef float f32x4 __attribute__((ext_vector_type(4)));

__device__ __forceinline__ unsigned short f2bf(float f){   // RTN bf16
    unsigned u = __float_as_uint(f);
    unsigned r = u + 0x7fffu + ((u >> 16) & 1u);
    return (unsigned short)(r >> 16);
}
__device__ __forceinline__ float bf2f(unsigned short s){
    return __uint_as_float((unsigned)s << 16);
}

// ---------------- CSR build ----------------
__global__ void k_count(const int* __restrict__ ef, const int* __restrict__ er,
                        int* __restrict__ deg, int Ef, int Er)
{
    int Etot = Ef + Er;
    for (int e = blockIdx.x*blockDim.x + threadIdx.x; e < Etot; e += gridDim.x*blockDim.x) {
        int dst = (e < Ef) ? ef[Ef + e] : er[Er + (e - Ef)];
        atomicAdd(&deg[dst], 1);
    }
}

__global__ void k_chunk_sums(const int* __restrict__ deg, int* __restrict__ csum, int n)
{
    __shared__ int s[256];
    int t = threadIdx.x, i = blockIdx.x*256 + t;
    s[t] = (i < n) ? deg[i] : 0;
    __syncthreads();
    for (int off = 128; off > 0; off >>= 1) {
        if (t < off) s[t] += s[t + off];
        __syncthreads();
    }
    if (t == 0) csum[blockIdx.x] = s[0];
}

__global__ void k_scan_chunks(int* __restrict__ csum, int nch)
{
    __shared__ int s[1024];
    int t = threadIdx.x;
    int v = (t < nch) ? csum[t] : 0;
    s[t] = v; __syncthreads();
    for (int off = 1; off < 1024; off <<= 1) {
        int u = (t >= off) ? s[t - off] : 0;
        __syncthreads();
        s[t] += u;
        __syncthreads();
    }
    if (t < nch) csum[t] = s[t] - v;
}

__global__ void k_rowstart(const int* __restrict__ deg, const int* __restrict__ csum,
                           int* __restrict__ row_start, int* __restrict__ cursor, int n)
{
    __shared__ int s[256];
    int t = threadIdx.x, i = blockIdx.x*256 + t;
    int d = (i < n) ? deg[i] : 0;
    s[t] = d; __syncthreads();
    for (int off = 1; off < 256; off <<= 1) {
        int u = (t >= off) ? s[t - off] : 0;
        __syncthreads();
        s[t] += u;
        __syncthreads();
    }
    if (i <= n) {
        int rs = csum[blockIdx.x] + s[t] - d;
        row_start[i] = rs;
        cursor[i] = rs;
    }
}

__global__ void k_fill(const int* __restrict__ ef, const int* __restrict__ er,
                       int* __restrict__ cursor, unsigned* __restrict__ srcs,
                       int Ef, int Er, int n_nodes)
{
    int Etot = Ef + Er;
    if (blockIdx.x == 0 && threadIdx.x == 0) { srcs[Etot] = 0; srcs[Etot + 1] = 0; }
    for (int e = blockIdx.x*blockDim.x + threadIdx.x; e < Etot; e += gridDim.x*blockDim.x) {
        int src, dst, tt;
        if (e < Ef) { src = ef[e]; dst = ef[Ef + e]; tt = 0; }
        else { int e2 = e - Ef; src = er[e2]; dst = er[Er + e2]; tt = 1; }
        int pos = atomicAdd(&cursor[dst], 1);
        srcs[pos] = (unsigned)(tt*n_nodes + src)*32u;
    }
}

// ---------------- mega setup ----------------
__global__ void k_setup(const float* __restrict__ kqv_w, const float* __restrict__ kqv_b,
                        const float* __restrict__ krel_w, const float* __restrict__ vrel_w,
                        const float* __restrict__ p_rel, const float* __restrict__ out_w,
                        const float* __restrict__ out_b, const float* __restrict__ in_w,
                        const float* __restrict__ x, const float* __restrict__ head_b,
                        unsigned short* __restrict__ WcT, float* __restrict__ biasc,
                        unsigned short* __restrict__ WoT, float* __restrict__ biaso,
                        unsigned short* __restrict__ WiT, unsigned short* __restrict__ x16,
                        int* __restrict__ deg, float* __restrict__ logits, int n_nodes)
{
    const int N0 = 2*129*640;            // compose kqv
    const int N1 = N0 + 2*129*128;       // compose out
    const int N2 = N1 + 128*128;         // in_w transpose
    const long long N3 = (long long)N2 + (long long)n_nodes*32;  // x cast (4/thread)
    const long long N4 = N3 + n_nodes;   // deg zero
    const long long N5 = N4 + 2*n_nodes; // logits init

    for (long long idx = (long long)blockIdx.x*blockDim.x + threadIdx.x; idx < N5;
         idx += (long long)gridDim.x*blockDim.x) {
        if (idx < N0) {
            int i = (int)idx;
            int l = i / (129*640);
            int rem = i % (129*640);
            int r = rem / 640, c = rem % 640;
            float val;
            if (c < 128) {
                val = (r < 128) ? kqv_w[((size_t)l*128 + r)*384 + 128 + c]
                                : kqv_b[l*384 + 128 + c];
            } else {
                int c2 = c - 128;
                int tt = c2 >> 8;
                int cc = c2 & 255;
                int f = cc >> 1;
                int part = cc & 1;
                int hh = f >> 4, fd = f & 15;
                const float* rw = (part == 0 ? krel_w : vrel_w)
                                  + (((size_t)(l*2 + tt)*8 + hh)*16)*16 + fd;
                int base_col = (part == 0 ? 0 : 256) + hh*16;
                float s = 0.f;
                #pragma unroll
                for (int d = 0; d < 16; ++d) {
                    float a = (r < 128) ? kqv_w[((size_t)l*128 + r)*384 + base_col + d]
                                        : kqv_b[l*384 + base_col + d];
                    s += a * rw[d*16];
                }
                if (part == 0) s *= p_rel[(l*2 + tt)*8 + hh] * 0.25f * 1.4426950408889634f;
                val = s;
            }
            if (r < 128) WcT[((size_t)l*640 + c)*128 + r] = f2bf(val);
            else         biasc[l*640 + c] = val;
        } else if (idx < N1) {
            int i = (int)(idx - N0);
            int l = i / (129*128);
            int rem = i % (129*128);
            int r = rem / 128, c = rem % 128;
            if (r < 128) WoT[((size_t)l*128 + c)*128 + r] = f2bf(out_w[((size_t)l*128 + r)*128 + c]);
            else         biaso[l*128 + c] = out_b[l*128 + c];
        } else if (idx < N2) {
            int i = (int)(idx - N1);
            int r = i >> 7, c = i & 127;
            WiT[(size_t)c*128 + r] = f2bf(in_w[(size_t)r*128 + c]);
        } else if (idx < N3) {
            long long i = idx - N2;
            float4 v = *(const float4*)&x[i*4];
            uint2 w;
            w.x = (unsigned)f2bf(v.x) | ((unsigned)f2bf(v.y) << 16);
            w.y = (unsigned)f2bf(v.z) | ((unsigned)f2bf(v.w) << 16);
            *(uint2*)&x16[i*4] = w;
        } else if (idx < N4) {
            deg[idx - N3] = 0;
        } else {
            long long i = idx - N4;
            logits[i] = head_b[i & 1];
        }
    }
}

// ---------------- LDS-staged MFMA GEMM (all-bf16 activations) ----------------
// mode 0 (in_proj): h16 = bf16(C+b)                        [packed pair stores]
// mode 1 (kqv): cols<128 -> q16 packed bf16; cols>=128 -> packed bf16 kv
// mode 2 (out_proj l0): nv = relu(g*(C+b) + (1-g)*bf(h16)); h16 = bf16(nv)
// mode 3 (out_proj l1 + head): nv = relu(...); logits[m] += nv . head_w
__global__ __launch_bounds__(256) void k_mfma(
    const unsigned short* __restrict__ A16, const unsigned short* __restrict__ WT,
    const float* __restrict__ biasc, unsigned short* __restrict__ q16,
    unsigned short* __restrict__ h16, unsigned* __restrict__ kv,
    const float* __restrict__ skip, const float* __restrict__ hw,
    float* __restrict__ logits, int l,
    int n_nodes, int R, int C, int mode)
{
    __shared__ uint4 As[64*16];
    __shared__ uint4 Ws[64*16];
    int b = blockIdx.x;
    int xcd = b & 7, jj = b >> 3;
    int r_t = (jj / C)*8 + xcd;
    int c_t = jj % C;
    if (r_t >= R) return;
    int n0 = r_t*64, c0 = c_t*64;
    int t = threadIdx.x;

    #pragma unroll
    for (int it = 0; it < 4; ++it) {
        int gi = t + it*256;
        int m = gi >> 4, g = gi & 15;
        uint4 a = *(const uint4*)&A16[((size_t)(n0 + m)*16 + g)*8];
        As[m*16 + (g ^ (m & 15))] = a;
    }
    #pragma unroll
    for (int it = 0; it < 4; ++it) {
        int gi = t + it*256;
        int cw = gi >> 4, g = gi & 15;
        uint4 wv = *(const uint4*)&WT[((size_t)(c0 + cw)*16 + g)*8];
        Ws[cw*16 + (g ^ (cw & 15))] = wv;
    }
    __syncthreads();

    int lane = t & 63, w = t >> 6;
    int lm = lane & 15, quad = lane >> 4;
    f32x4 acc[4];
    #pragma unroll
    for (int i = 0; i < 4; ++i) { acc[i][0]=0.f; acc[i][1]=0.f; acc[i][2]=0.f; acc[i][3]=0.f; }

    #pragma unroll
    for (int chunk = 0; chunk < 4; ++chunk) {
        int gq = chunk*4 + quad;
        short8 bfrag = *(const short8*)&Ws[(w*16 + lm)*16 + (gq ^ lm)];
        #pragma unroll
        for (int i = 0; i < 4; ++i) {
            short8 afrag = *(const short8*)&As[(i*16 + lm)*16 + (gq ^ lm)];
            acc[i] = __builtin_amdgcn_mfma_f32_16x16x32_bf16(afrag, bfrag, acc[i], 0, 0, 0);
        }
    }

    int c = c0 + w*16 + lm;
    float bc = biasc[c];
    bool even = (lane & 1) == 0;
    if (mode == 3) {
        float g = 1.f/(1.f + expf(-skip[l]));
        float hw0 = hw[c*2], hw1 = hw[c*2 + 1];
        #pragma unroll
        for (int i = 0; i < 4; ++i) {
            #pragma unroll
            for (int rr = 0; rr < 4; ++rr) {
                int m = n0 + i*16 + quad*4 + rr;
                float nv = 0.f;
                if (m < n_nodes) {
                    float hv = bf2f(h16[(size_t)m*128 + c]);
                    nv = fmaxf(g*(acc[i][rr] + bc) + (1.f - g)*hv, 0.f);
                }
                float p0 = nv*hw0, p1 = nv*hw1;
                p0 += __shfl_xor(p0, 1); p1 += __shfl_xor(p1, 1);
                p0 += __shfl_xor(p0, 2); p1 += __shfl_xor(p1, 2);
                p0 += __shfl_xor(p0, 4); p1 += __shfl_xor(p1, 4);
                p0 += __shfl_xor(p0, 8); p1 += __shfl_xor(p1, 8);
                if (lm == 0 && m < n_nodes) {
                    atomicAdd(&logits[m*2],     p0);
                    atomicAdd(&logits[m*2 + 1], p1);
                }
            }
        }
    } else if (mode == 2) {
        float g = 1.f/(1.f + expf(-skip[l]));
        unsigned* dst = (unsigned*)h16;
        #pragma unroll
        for (int i = 0; i < 4; ++i) {
            #pragma unroll
            for (int rr = 0; rr < 4; ++rr) {
                int m = n0 + i*16 + quad*4 + rr;
                float hv = (m < n_nodes) ? bf2f(h16[(size_t)m*128 + c]) : 0.f;
                float nv = fmaxf(g*(acc[i][rr] + bc) + (1.f - g)*hv, 0.f);
                float other = __shfl_xor(nv, 1);
                if (even && m < n_nodes)
                    dst[(size_t)m*64 + (c >> 1)] =
                        (unsigned)f2bf(nv) | ((unsigned)f2bf(other) << 16);
            }
        }
    } else if (mode == 0) {
        unsigned* dst = (unsigned*)h16;
        #pragma unroll
        for (int i = 0; i < 4; ++i) {
            #pragma unroll
            for (int rr = 0; rr < 4; ++rr) {
                int m = n0 + i*16 + quad*4 + rr;
                float nv = acc[i][rr] + bc;
                float other = __shfl_xor(nv, 1);
                if (even && m < n_nodes)
                    dst[(size_t)m*64 + (c >> 1)] =
                        (unsigned)f2bf(nv) | ((unsigned)f2bf(other) << 16);
            }
        }
    } else if (c0 < 128) {                 // kqv: q columns -> packed bf16 q16
        unsigned* dst = (unsigned*)q16;
        #pragma unroll
        for (int i = 0; i < 4; ++i) {
            #pragma unroll
            for (int rr = 0; rr < 4; ++rr) {
                float val = acc[i][rr] + bc;
                float other = __shfl_xor(val, 1);
                int m = n0 + i*16 + quad*4 + rr;
                if (even && m < n_nodes)
                    dst[(size_t)m*64 + (c >> 1)] =
                        (unsigned)f2bf(val) | ((unsigned)f2bf(other) << 16);
            }
        }
    } else {                               // kqv: packed bf16 kv (k high, v low)
        int c2 = c - 128;
        int tt = c2 >> 8;
        int f = (c2 & 255) >> 1;
        unsigned* dst = kv + (size_t)tt*n_nodes*128;
        #pragma unroll
        for (int i = 0; i < 4; ++i) {
            #pragma unroll
            for (int rr = 0; rr < 4; ++rr) {
                float val = acc[i][rr] + bc;
                float other = __shfl_xor(val, 1);
                int m = n0 + i*16 + quad*4 + rr;
                if (even && m < n_nodes) {
                    unsigned wd = ((unsigned)f2bf(val) << 16) | (unsigned)f2bf(other);
                    dst[(size_t)m*128 + f] = wd;
                }
            }
        }
    }
}

// ---------------- fused gather attention (bf16 q; exp2; gelu -> bf16 qa16) ----------------
__global__ __launch_bounds__(256) void k_attn(
    const unsigned* __restrict__ srcs, const int* __restrict__ row_start,
    const uint4* __restrict__ kv, const unsigned short* __restrict__ q16,
    unsigned short* __restrict__ qa16, int n_nodes)
{
    int lane = threadIdx.x & 31;
    int n = blockIdx.x*8 + (threadIdx.x >> 5);
    if (n >= n_nodes) return;
    uint2 qp = *(const uint2*)&q16[(size_t)n*128 + lane*4];
    float4 q4;
    q4.x = __uint_as_float(qp.x << 16);
    q4.y = __uint_as_float(qp.x & 0xffff0000u);
    q4.z = __uint_as_float(qp.y << 16);
    q4.w = __uint_as_float(qp.y & 0xffff0000u);
    int s = row_start[n], e = row_start[n + 1];

    float m0 = -INFINITY, l0 = 0.f; float4 a0 = make_float4(0.f,0.f,0.f,0.f);
    float m1 = -INFINITY, l1 = 0.f; float4 a1 = make_float4(0.f,0.f,0.f,0.f);

    uint4 w0n = kv[srcs[s] + lane];
    uint4 w1n = kv[srcs[s + 1] + lane];
    int pos = s;
    for (; pos + 1 < e; pos += 2) {
        uint4 w0 = w0n, w1 = w1n;
        unsigned sv0 = srcs[pos + 2], sv1 = srcs[pos + 3];
        w0n = kv[sv0 + lane];
        w1n = kv[sv1 + lane];
        float d0 = __uint_as_float(w0.x & 0xffff0000u)*q4.x
                 + __uint_as_float(w0.y & 0xffff0000u)*q4.y
                 + __uint_as_float(w0.z & 0xffff0000u)*q4.z
                 + __uint_as_float(w0.w & 0xffff0000u)*q4.w;
        float d1 = __uint_as_float(w1.x & 0xffff0000u)*q4.x
                 + __uint_as_float(w1.y & 0xffff0000u)*q4.y
                 + __uint_as_float(w1.z & 0xffff0000u)*q4.z
                 + __uint_as_float(w1.w & 0xffff0000u)*q4.w;
        d0 += __shfl_xor(d0, 1); d1 += __shfl_xor(d1, 1);
        d0 += __shfl_xor(d0, 2); d1 += __shfl_xor(d1, 2);
        float mn0 = fmaxf(m0, d0), mn1 = fmaxf(m1, d1);
        float sc0 = exp2f(m0 - mn0), sc1 = exp2f(m1 - mn1);
        float wt0 = exp2f(d0 - mn0), wt1 = exp2f(d1 - mn1);
        l0 = l0*sc0 + wt0;               l1 = l1*sc1 + wt1;
        a0.x = a0.x*sc0 + wt0*__uint_as_float(w0.x << 16);
        a1.x = a1.x*sc1 + wt1*__uint_as_float(w1.x << 16);
        a0.y = a0.y*sc0 + wt0*__uint_as_float(w0.y << 16);
        a1.y = a1.y*sc1 + wt1*__uint_as_float(w1.y << 16);
        a0.z = a0.z*sc0 + wt0*__uint_as_float(w0.z << 16);
        a1.z = a1.z*sc1 + wt1*__uint_as_float(w1.z << 16);
        a0.w = a0.w*sc0 + wt0*__uint_as_float(w0.w << 16);
        a1.w = a1.w*sc1 + wt1*__uint_as_float(w1.w << 16);
        m0 = mn0; m1 = mn1;
    }
    if (pos < e) {
        uint4 w0 = w0n;
        float d = __uint_as_float(w0.x & 0xffff0000u)*q4.x
                + __uint_as_float(w0.y & 0xffff0000u)*q4.y
                + __uint_as_float(w0.z & 0xffff0000u)*q4.z
                + __uint_as_float(w0.w & 0xffff0000u)*q4.w;
        d += __shfl_xor(d, 1);
        d += __shfl_xor(d, 2);
        float mn = fmaxf(m0, d);
        float sc = exp2f(m0 - mn);
        float wt = exp2f(d - mn);
        l0 = l0*sc + wt;
        a0.x = a0.x*sc + wt*__uint_as_float(w0.x << 16);
        a0.y = a0.y*sc + wt*__uint_as_float(w0.y << 16);
        a0.z = a0.z*sc + wt*__uint_as_float(w0.z << 16);
        a0.w = a0.w*sc + wt*__uint_as_float(w0.w << 16);
        m0 = mn;
    }
    float mn = fmaxf(m0, m1);
    float sc0 = (m0 == -INFINITY) ? 0.f : exp2f(m0 - mn);
    float sc1 = (m1 == -INFINITY) ? 0.f : exp2f(m1 - mn);
    float lsum = l0*sc0 + l1*sc1;
    float4 acc;
    acc.x = a0.x*sc0 + a1.x*sc1;
    acc.y = a0.y*sc0 + a1.y*sc1;
    acc.z = a0.z*sc0 + a1.z*sc1;
    acc.w = a0.w*sc0 + a1.w*sc1;

    float inv = 1.f/(lsum + 1e-16f);
    float x0 = acc.x*inv, x1 = acc.y*inv, x2 = acc.z*inv, x3 = acc.w*inv;
    float g0 = 0.5f*x0*(1.f + erff(x0*0.70710678118654752f));
    float g1 = 0.5f*x1*(1.f + erff(x1*0.70710678118654752f));
    float g2 = 0.5f*x2*(1.f + erff(x2*0.70710678118654752f));
    float g3 = 0.5f*x3*(1.f + erff(x3*0.70710678118654752f));
    uint2 pk;
    pk.x = (unsigned)f2bf(g0) | ((unsigned)f2bf(g1) << 16);
    pk.y = (unsigned)f2bf(g2) | ((unsigned)f2bf(g3) << 16);
    *(uint2*)&qa16[(size_t)n*128 + lane*4] = pk;
}

extern "C" void kernel_launch(void* const* d_in, const int* in_sizes, int n_in,
                              void* d_out, int out_size, void* d_ws, size_t ws_size,
                              hipStream_t stream)
{
    const float* x      = (const float*)d_in[0];
    const int*   ef     = (const int*)d_in[1];
    const int*   er     = (const int*)d_in[2];
    const float* in_w   = (const float*)d_in[3];
    const float* in_b   = (const float*)d_in[4];
    const float* kqv_w  = (const float*)d_in[5];
    const float* kqv_b  = (const float*)d_in[6];
    const float* krel_w = (const float*)d_in[7];
    const float* vrel_w = (const float*)d_in[8];
    const float* p_rel  = (const float*)d_in[9];
    const float* out_w  = (const float*)d_in[10];
    const float* out_b  = (const float*)d_in[11];
    const float* skip   = (const float*)d_in[12];
    const float* head_w = (const float*)d_in[13];
    const float* head_b = (const float*)d_in[14];
    float* out = (float*)d_out;

    int n_nodes = in_sizes[0] / 128;
    int Ef = in_sizes[1] / 2, Er = in_sizes[2] / 2;
    int Etot = Ef + Er;
    int nch = (n_nodes + 255)/256;
    int ntile = (n_nodes + 63)/64;
    int npad = ntile*64;

    // workspace (all activations bf16)
    float* p = (float*)d_ws;
    unsigned* kv = (unsigned*)p; p += (size_t)2*n_nodes*128;
    unsigned short* h16  = (unsigned short*)p; p += (size_t)npad*128/2;
    unsigned short* q16  = (unsigned short*)p; p += (size_t)npad*128/2;
    unsigned short* qa16 = (unsigned short*)p; p += (size_t)npad*128/2;
    unsigned short* x16  = (unsigned short*)p; p += (size_t)npad*128/2;
    unsigned short* WiT = (unsigned short*)p; p += (size_t)(128*128)/2;
    unsigned short* WcT = (unsigned short*)p; p += (size_t)(2*640*128)/2;
    float* biasc = p; p += 2*640;
    unsigned short* WoT = (unsigned short*)p; p += (size_t)(2*128*128)/2;
    float* biaso = p; p += 2*128;
    int* deg       = (int*)p;      p += n_nodes;
    int* csum      = (int*)p;      p += 1024;
    int* row_start = (int*)p;      p += n_nodes + 1;
    int* cursor    = (int*)p;      p += n_nodes + 1;
    unsigned* srcs = (unsigned*)p; p += Etot + 2;

    int Rg = (ntile + 7)/8;

    // ---- setup + CSR build ----
    k_setup<<<7500, 256, 0, stream>>>(kqv_w, kqv_b, krel_w, vrel_w, p_rel, out_w, out_b,
                                      in_w, x, head_b, WcT, biasc, WoT, biaso, WiT, x16,
                                      deg, out, n_nodes);
    k_count<<<1024, 256, 0, stream>>>(ef, er, deg, Ef, Er);
    k_chunk_sums<<<nch, 256, 0, stream>>>(deg, csum, n_nodes);
    k_scan_chunks<<<1, 1024, 0, stream>>>(csum, nch);
    k_rowstart<<<(n_nodes + 256)/256, 256, 0, stream>>>(deg, csum, row_start, cursor, n_nodes);
    k_fill<<<1024, 256, 0, stream>>>(ef, er, cursor, srcs, Ef, Er, n_nodes);

    // ---- network ----
    k_mfma<<<Rg*8*2, 256, 0, stream>>>(x16, WiT, in_b, nullptr, h16, kv, skip,
                                       head_w, out, 0, n_nodes, ntile, 2, 0);
    for (int l = 0; l < 2; ++l) {
        k_mfma<<<Rg*8*10, 256, 0, stream>>>(h16, WcT + (size_t)l*640*128,
                                            biasc + l*640, q16, nullptr, kv, skip,
                                            head_w, out, l, n_nodes, ntile, 10, 1);
        k_attn<<<(n_nodes + 7)/8, 256, 0, stream>>>(srcs, row_start,
                                                    (const uint4*)kv, q16, qa16, n_nodes);
        int omode = (l == 1) ? 3 : 2;
        k_mfma<<<Rg*8*2, 256, 0, stream>>>(qa16, WoT + (size_t)l*128*128,
                                           biaso + l*128, nullptr, h16, kv, skip,
                                           head_w, out, l, n_nodes, ntile, 2, omode);
    }
}